// Round 10
// baseline (242.316 us; speedup 1.0000x reference)
//
#include <hip/hip_runtime.h>
#include <cmath>

#define DCOL 768
#define KCH 96            // DCOL/8
#define FTHREADS 768

typedef __attribute__((ext_vector_type(8))) short bf16x8;

__device__ __forceinline__ short f2bf(float f) {
    return (short)(__builtin_bit_cast(unsigned, f) >> 16);
}
__device__ __forceinline__ float bf2f(short s) {
    unsigned u = ((unsigned)(unsigned short)s) << 16;
    return __builtin_bit_cast(float, u);
}

__device__ __forceinline__ int lower_bound_i(const int* __restrict__ arr, int n, int val) {
    int lo = 0, hi = n;
    while (lo < hi) {
        int mid = (lo + hi) >> 1;
        if (arr[mid] < val) lo = mid + 1; else hi = mid;
    }
    return lo;
}

// ---- reshape weights: fp32 src[k][j] -> bf16 W3[((jg*KCH + kk)*64 + (j&63))*8 + ki]
// so a wave's GEMV step loads 64 lanes x 16B contiguous (1 KB coalesced).
__global__ void reshape_w(const float* __restrict__ src0, short* __restrict__ dst0,
                          const float* __restrict__ src1, short* __restrict__ dst1) {
    const float* __restrict__ src = blockIdx.z ? src1 : src0;
    short* __restrict__ dst = blockIdx.z ? dst1 : dst0;
    int t = blockIdx.x * 256 + threadIdx.x;     // [0, 12*KCH*64)
    int lane = t & 63;
    int kk8 = (t >> 6) % KCH;
    int jg = t / (KCH * 64);
    int j = jg * 64 + lane;
    bf16x8 w;
    #pragma unroll
    for (int ki = 0; ki < 8; ++ki)
        w[ki] = f2bf(src[(size_t)(kk8 * 8 + ki) * DCOL + j]);
    *(bf16x8*)(dst + (size_t)t * 8) = w;
}

// ---- GEMV dot: thread (wid,lane) computes output j = wid*64+lane.
__device__ __forceinline__ float gemv_dot(const short* __restrict__ W3,
                                          const float* __restrict__ xs,
                                          int wid, int lane) {
    const bf16x8* __restrict__ wp = (const bf16x8*)W3 + (size_t)wid * (KCH * 64) + lane;
    float acc = 0.f;
    #pragma unroll 8
    for (int kk = 0; kk < KCH; ++kk) {
        bf16x8 w = wp[(size_t)kk * 64];
        const float* xk = xs + kk * 8;
        float4 xa = *(const float4*)(xk);
        float4 xb = *(const float4*)(xk + 4);
        acc += bf2f(w[0]) * xa.x + bf2f(w[1]) * xa.y + bf2f(w[2]) * xa.z + bf2f(w[3]) * xa.w
             + bf2f(w[4]) * xb.x + bf2f(w[5]) * xb.y + bf2f(w[6]) * xb.z + bf2f(w[7]) * xb.w;
    }
    return acc;
}

// ---- fused per-graph kernel: pool -> GEMV1(+relu,+vn) -> GEMV2 -> re-read rows + y
// One block per graph; thread t owns column t. NO row holding: phase 4 re-reads
// the rows; the read->re-read window is only the ~5us GEMV phase, so the
// aggregate L3 traffic in between (~150 MB) < 256 MB Infinity Cache => L3 hits.
__global__ __launch_bounds__(FTHREADS) void fused_kernel(
        const float* __restrict__ feat, const float* __restrict__ vn,
        const int* __restrict__ batch,
        const short* __restrict__ W3fc, const float* __restrict__ fcb,
        const short* __restrict__ W3p, const float* __restrict__ pb,
        float* __restrict__ out_feat, float* __restrict__ out_vn, int N) {
    __shared__ float xbuf[DCOL];
    __shared__ float x2buf[DCOL];
    __shared__ int srange[2];

    const int g = blockIdx.x;
    const int t = threadIdx.x;
    if (t < 2) srange[t] = lower_bound_i(batch, N, g + t);
    __syncthreads();
    const int lo = srange[0], hi = srange[1];
    const int cnt = hi - lo;
    const float vnv = vn[(size_t)g * DCOL + t];

    const float* __restrict__ fp = feat + (size_t)lo * DCOL + t;

    // phase 1: column sum (normal loads -> allocate in L2/L3 for phase 4)
    float s0 = 0.f, s1 = 0.f, s2 = 0.f, s3 = 0.f;
    float s4 = 0.f, s5 = 0.f, s6 = 0.f, s7 = 0.f;
    int r = 0;
    for (; r + 8 <= cnt; r += 8) {
        float v0 = fp[(size_t)(r + 0) * DCOL];
        float v1 = fp[(size_t)(r + 1) * DCOL];
        float v2 = fp[(size_t)(r + 2) * DCOL];
        float v3 = fp[(size_t)(r + 3) * DCOL];
        float v4 = fp[(size_t)(r + 4) * DCOL];
        float v5 = fp[(size_t)(r + 5) * DCOL];
        float v6 = fp[(size_t)(r + 6) * DCOL];
        float v7 = fp[(size_t)(r + 7) * DCOL];
        s0 += v0; s1 += v1; s2 += v2; s3 += v3;
        s4 += v4; s5 += v5; s6 += v6; s7 += v7;
    }
    for (; r < cnt; ++r) s0 += fp[(size_t)r * DCOL];
    float sum = ((s0 + s1) + (s2 + s3)) + ((s4 + s5) + (s6 + s7));
    float scale = cnt > 0 ? (logf((float)cnt) / (float)cnt) : 0.f;
    xbuf[t] = sum * scale + vnv;
    __syncthreads();

    // phase 2: GEMV1  h = relu(x @ fcW + fcb); vn_new = vn + h
    const int wid = t >> 6, lane = t & 63;
    float h = gemv_dot(W3fc, xbuf, wid, lane) + fcb[t];
    h = fmaxf(h, 0.f);
    float vnn = vnv + h;
    out_vn[(size_t)g * DCOL + t] = vnn;
    x2buf[t] = vnn;
    __syncthreads();

    // phase 3: GEMV2  y = vn_new @ pW + pb   (y[t] stays in thread t's register)
    float y = gemv_dot(W3p, x2buf, wid, lane) + pb[t];

    // phase 4: re-read rows (L3-hot) + add y, nt store
    float* op = out_feat + (size_t)lo * DCOL + t;
    r = 0;
    for (; r + 4 <= cnt; r += 4) {
        float f0 = fp[(size_t)(r + 0) * DCOL];
        float f1 = fp[(size_t)(r + 1) * DCOL];
        float f2 = fp[(size_t)(r + 2) * DCOL];
        float f3 = fp[(size_t)(r + 3) * DCOL];
        __builtin_nontemporal_store(f0 + y, op + (size_t)(r + 0) * DCOL);
        __builtin_nontemporal_store(f1 + y, op + (size_t)(r + 1) * DCOL);
        __builtin_nontemporal_store(f2 + y, op + (size_t)(r + 2) * DCOL);
        __builtin_nontemporal_store(f3 + y, op + (size_t)(r + 3) * DCOL);
    }
    for (; r < cnt; ++r) {
        float f0 = fp[(size_t)r * DCOL];
        __builtin_nontemporal_store(f0 + y, op + (size_t)r * DCOL);
    }
}

extern "C" void kernel_launch(void* const* d_in, const int* in_sizes, int n_in,
                              void* d_out, int out_size, void* d_ws, size_t ws_size,
                              hipStream_t stream) {
    const float* feat  = (const float*)d_in[0];
    const float* vn    = (const float*)d_in[1];
    const float* edge  = (const float*)d_in[2];
    const int*   batch = (const int*)d_in[3];
    const float* fcW   = (const float*)d_in[5];
    const float* fcb   = (const float*)d_in[6];
    const float* pW    = (const float*)d_in[7];
    const float* pb    = (const float*)d_in[8];

    const int D = in_sizes[6];            // 768
    const int N = in_sizes[0] / D;        // 100000
    const int B = in_sizes[1] / D;        // 1024
    const int edge_elems = in_sizes[2];   // B*DE

    float* out_feat = (float*)d_out;
    float* out_vn   = out_feat + (size_t)N * D;
    float* out_edge = out_vn + (size_t)B * D;

    char* ws = (char*)d_ws;
    short* W3fc = (short*)ws;                                 // [12*96*64*8] bf16
    short* W3p  = (short*)(ws + (size_t)12 * KCH * 64 * 8 * 2);

    // 0) reshape both weight matrices to the GEMV-coalesced bf16 layout
    dim3 rg(12 * KCH * 64 / 256, 1, 2);
    reshape_w<<<rg, 256, 0, stream>>>(fcW, W3fc, pW, W3p);

    // 1) fused pool + FC + project + broadcast-add (one block per graph)
    fused_kernel<<<B, FTHREADS, 0, stream>>>(feat, vn, batch, W3fc, fcb, W3p, pb,
                                             out_feat, out_vn, N);

    // 2) edge passthrough
    hipMemcpyAsync(out_edge, edge, (size_t)edge_elems * sizeof(float),
                   hipMemcpyDeviceToDevice, stream);
}

// Round 11
// 239.535 us; speedup vs baseline: 1.0116x; 1.0116x over previous
//
#include <hip/hip_runtime.h>
#include <cmath>

#define DCOL 768
#define D4C 192           // DCOL/4 float4 columns
#define KCH 96            // DCOL/8
#define FTHREADS 768

typedef __attribute__((ext_vector_type(8))) short bf16x8;
typedef __attribute__((ext_vector_type(4))) float f32x4;

__device__ __forceinline__ short f2bf(float f) {
    return (short)(__builtin_bit_cast(unsigned, f) >> 16);
}
__device__ __forceinline__ float bf2f(short s) {
    unsigned u = ((unsigned)(unsigned short)s) << 16;
    return __builtin_bit_cast(float, u);
}

__device__ __forceinline__ int lower_bound_i(const int* __restrict__ arr, int n, int val) {
    int lo = 0, hi = n;
    while (lo < hi) {
        int mid = (lo + hi) >> 1;
        if (arr[mid] < val) lo = mid + 1; else hi = mid;
    }
    return lo;
}

__device__ __forceinline__ float4 f4add(float4 a, float4 b) {
    a.x += b.x; a.y += b.y; a.z += b.z; a.w += b.w; return a;
}

// ---- reshape weights: fp32 src[k][j] -> bf16 W3[((jg*KCH + kk)*64 + (j&63))*8 + ki]
__global__ void reshape_w(const float* __restrict__ src0, short* __restrict__ dst0,
                          const float* __restrict__ src1, short* __restrict__ dst1) {
    const float* __restrict__ src = blockIdx.z ? src1 : src0;
    short* __restrict__ dst = blockIdx.z ? dst1 : dst0;
    int t = blockIdx.x * 256 + threadIdx.x;     // [0, 12*KCH*64)
    int lane = t & 63;
    int kk8 = (t >> 6) % KCH;
    int jg = t / (KCH * 64);
    int j = jg * 64 + lane;
    bf16x8 w;
    #pragma unroll
    for (int ki = 0; ki < 8; ++ki)
        w[ki] = f2bf(src[(size_t)(kk8 * 8 + ki) * DCOL + j]);
    *(bf16x8*)(dst + (size_t)t * 8) = w;
}

// ---- GEMV dot: thread (wid,lane) computes output j = wid*64+lane.
__device__ __forceinline__ float gemv_dot(const short* __restrict__ W3,
                                          const float* __restrict__ xs,
                                          int wid, int lane) {
    const bf16x8* __restrict__ wp = (const bf16x8*)W3 + (size_t)wid * (KCH * 64) + lane;
    float acc = 0.f;
    #pragma unroll 8
    for (int kk = 0; kk < KCH; ++kk) {
        bf16x8 w = wp[(size_t)kk * 64];
        const float* xk = xs + kk * 8;
        float4 xa = *(const float4*)(xk);
        float4 xb = *(const float4*)(xk + 4);
        acc += bf2f(w[0]) * xa.x + bf2f(w[1]) * xa.y + bf2f(w[2]) * xa.z + bf2f(w[3]) * xa.w
             + bf2f(w[4]) * xb.x + bf2f(w[5]) * xb.y + bf2f(w[6]) * xb.z + bf2f(w[7]) * xb.w;
    }
    return acc;
}

// ---- fused per-graph kernel, float4-vectorized streaming phases ----
// Streaming phases: thread = (c, rr) with c = float4 column, rr = row offset mod 4.
// GEMV phases: thread t = output column t. y parked in LDS between phases.
__global__ __launch_bounds__(FTHREADS) void fused_kernel(
        const float4* __restrict__ feat4, const float* __restrict__ vn,
        const int* __restrict__ batch,
        const short* __restrict__ W3fc, const float* __restrict__ fcb,
        const short* __restrict__ W3p, const float* __restrict__ pb,
        float* __restrict__ out_feat, float* __restrict__ out_vn, int N) {
    __shared__ __align__(16) float part[4][DCOL];   // 12 KB: per-rr float4 partials
    __shared__ __align__(16) float xbuf[DCOL];
    __shared__ __align__(16) float x2buf[DCOL];
    __shared__ __align__(16) float ybuf[DCOL];
    __shared__ int srange[2];

    const int g = blockIdx.x;
    const int t = threadIdx.x;
    if (t < 2) srange[t] = lower_bound_i(batch, N, g + t);
    __syncthreads();
    const int lo = srange[0], hi = srange[1];
    const int cnt = hi - lo;

    const int c = t % D4C;      // float4 column 0..191
    const int rr = t / D4C;     // 0..3

    // ---- phase 1: column sums; rows rr, rr+4, ... (8 float4 loads in flight) ----
    const float4* __restrict__ fp4 = feat4 + (size_t)lo * D4C + c;
    float4 a0 = {0,0,0,0}, a1 = {0,0,0,0}, a2 = {0,0,0,0}, a3 = {0,0,0,0};
    float4 a4 = {0,0,0,0}, a5 = {0,0,0,0}, a6 = {0,0,0,0}, a7 = {0,0,0,0};
    int k = rr;
    for (; k + 28 < cnt; k += 32) {
        float4 v0 = fp4[(size_t)(k +  0) * D4C];
        float4 v1 = fp4[(size_t)(k +  4) * D4C];
        float4 v2 = fp4[(size_t)(k +  8) * D4C];
        float4 v3 = fp4[(size_t)(k + 12) * D4C];
        float4 v4 = fp4[(size_t)(k + 16) * D4C];
        float4 v5 = fp4[(size_t)(k + 20) * D4C];
        float4 v6 = fp4[(size_t)(k + 24) * D4C];
        float4 v7 = fp4[(size_t)(k + 28) * D4C];
        a0 = f4add(a0, v0); a1 = f4add(a1, v1); a2 = f4add(a2, v2); a3 = f4add(a3, v3);
        a4 = f4add(a4, v4); a5 = f4add(a5, v5); a6 = f4add(a6, v6); a7 = f4add(a7, v7);
    }
    for (; k < cnt; k += 4) a0 = f4add(a0, fp4[(size_t)k * D4C]);
    float4 s = f4add(f4add(f4add(a0, a1), f4add(a2, a3)), f4add(f4add(a4, a5), f4add(a6, a7)));
    *(float4*)&part[rr][c * 4] = s;
    __syncthreads();

    // reduce across rr, scale, add vn -> xbuf (192 threads)
    if (t < D4C) {
        float4 p0 = *(const float4*)&part[0][t * 4];
        float4 p1 = *(const float4*)&part[1][t * 4];
        float4 p2 = *(const float4*)&part[2][t * 4];
        float4 p3 = *(const float4*)&part[3][t * 4];
        float4 ss = f4add(f4add(p0, p1), f4add(p2, p3));
        float scale = cnt > 0 ? (logf((float)cnt) / (float)cnt) : 0.f;
        float4 vnv = *(const float4*)(vn + (size_t)g * DCOL + t * 4);
        float4 x;
        x.x = ss.x * scale + vnv.x; x.y = ss.y * scale + vnv.y;
        x.z = ss.z * scale + vnv.z; x.w = ss.w * scale + vnv.w;
        *(float4*)&xbuf[t * 4] = x;
    }
    __syncthreads();

    // ---- phase 2: GEMV1  h = relu(x @ fcW + fcb); vn_new = vn + h ----
    const int wid = t >> 6, lane = t & 63;
    float h = gemv_dot(W3fc, xbuf, wid, lane) + fcb[t];
    h = fmaxf(h, 0.f);
    float vnn = vn[(size_t)g * DCOL + t] + h;
    out_vn[(size_t)g * DCOL + t] = vnn;
    x2buf[t] = vnn;
    __syncthreads();

    // ---- phase 3: GEMV2  y = vn_new @ pW + pb ----
    ybuf[t] = gemv_dot(W3p, x2buf, wid, lane) + pb[t];
    __syncthreads();

    // ---- phase 4: re-read rows (L3-hot window) + add y, nt float4 stores ----
    float4 y4 = *(const float4*)&ybuf[c * 4];
    float* op = out_feat + ((size_t)lo + 0) * DCOL + c * 4;
    k = rr;
    for (; k + 12 < cnt; k += 16) {
        float4 f0 = fp4[(size_t)(k +  0) * D4C];
        float4 f1 = fp4[(size_t)(k +  4) * D4C];
        float4 f2 = fp4[(size_t)(k +  8) * D4C];
        float4 f3 = fp4[(size_t)(k + 12) * D4C];
        f32x4 r0, r1, r2, r3;
        r0.x = f0.x + y4.x; r0.y = f0.y + y4.y; r0.z = f0.z + y4.z; r0.w = f0.w + y4.w;
        r1.x = f1.x + y4.x; r1.y = f1.y + y4.y; r1.z = f1.z + y4.z; r1.w = f1.w + y4.w;
        r2.x = f2.x + y4.x; r2.y = f2.y + y4.y; r2.z = f2.z + y4.z; r2.w = f2.w + y4.w;
        r3.x = f3.x + y4.x; r3.y = f3.y + y4.y; r3.z = f3.z + y4.z; r3.w = f3.w + y4.w;
        __builtin_nontemporal_store(r0, (f32x4*)(op + (size_t)(k +  0) * DCOL));
        __builtin_nontemporal_store(r1, (f32x4*)(op + (size_t)(k +  4) * DCOL));
        __builtin_nontemporal_store(r2, (f32x4*)(op + (size_t)(k +  8) * DCOL));
        __builtin_nontemporal_store(r3, (f32x4*)(op + (size_t)(k + 12) * DCOL));
    }
    for (; k < cnt; k += 4) {
        float4 f0 = fp4[(size_t)k * D4C];
        f32x4 r0;
        r0.x = f0.x + y4.x; r0.y = f0.y + y4.y; r0.z = f0.z + y4.z; r0.w = f0.w + y4.w;
        __builtin_nontemporal_store(r0, (f32x4*)(op + (size_t)k * DCOL));
    }
}

extern "C" void kernel_launch(void* const* d_in, const int* in_sizes, int n_in,
                              void* d_out, int out_size, void* d_ws, size_t ws_size,
                              hipStream_t stream) {
    const float* feat  = (const float*)d_in[0];
    const float* vn    = (const float*)d_in[1];
    const float* edge  = (const float*)d_in[2];
    const int*   batch = (const int*)d_in[3];
    const float* fcW   = (const float*)d_in[5];
    const float* fcb   = (const float*)d_in[6];
    const float* pW    = (const float*)d_in[7];
    const float* pb    = (const float*)d_in[8];

    const int D = in_sizes[6];            // 768
    const int N = in_sizes[0] / D;        // 100000
    const int B = in_sizes[1] / D;        // 1024
    const int edge_elems = in_sizes[2];   // B*DE

    float* out_feat = (float*)d_out;
    float* out_vn   = out_feat + (size_t)N * D;
    float* out_edge = out_vn + (size_t)B * D;

    char* ws = (char*)d_ws;
    short* W3fc = (short*)ws;                                 // [12*96*64*8] bf16
    short* W3p  = (short*)(ws + (size_t)12 * KCH * 64 * 8 * 2);

    // 0) reshape both weight matrices to the GEMV-coalesced bf16 layout
    dim3 rg(12 * KCH * 64 / 256, 1, 2);
    reshape_w<<<rg, 256, 0, stream>>>(fcW, W3fc, pW, W3p);

    // 1) fused pool + FC + project + broadcast-add (one block per graph)
    fused_kernel<<<B, FTHREADS, 0, stream>>>((const float4*)feat, vn, batch,
                                             W3fc, fcb, W3p, pb,
                                             out_feat, out_vn, N);

    // 2) edge passthrough
    hipMemcpyAsync(out_edge, edge, (size_t)edge_elems * sizeof(float),
                   hipMemcpyDeviceToDevice, stream);
}